// Round 6
// baseline (1889.331 us; speedup 1.0000x reference)
//
#include <hip/hip_runtime.h>
#include <hip/hip_cooperative_groups.h>

namespace cg = cooperative_groups;

#define TAU 0.25f
#define SIGMA 0.5f

typedef _Float16 fp16;
typedef fp16 half8 __attribute__((ext_vector_type(8)));

constexpr int H = 1024, W = 1024, C = 3;
constexpr int N   = H * W * C;     // 3,145,728
constexpr int WC  = W * C;         // 3072 elems per row
constexpr int VEC = 8;
constexpr int CPR = WC / VEC;      // 384 chunks per row
constexpr int TPB = 768;           // threads per block (2 chunks/thread)
constexpr int RB  = 4;             // rows per block
constexpr int NB  = H / RB;        // 256 blocks = 1 per CU
constexpr int ITS = 20;

__device__ __forceinline__ float clampw(float v, float w) {
    return fminf(fmaxf(v, -w), w);
}

__device__ __forceinline__ void ld8(const float* __restrict__ p, int i, float* v) {
    float4 a = *(const float4*)(p + i);
    float4 b = *(const float4*)(p + i + 4);
    v[0]=a.x; v[1]=a.y; v[2]=a.z; v[3]=a.w;
    v[4]=b.x; v[5]=b.y; v[6]=b.z; v[7]=b.w;
}

// Persistent cooperative kernel: all 20 CP iterations; state lives in LDS.
// Per iteration: dual (px,py update; shadow py row y0-1 recomputed locally,
// bitwise-identical to the neighbor's own calc) -> barrier -> primal
// (u, ubar update) + publish boundary ub rows -> grid sync -> import halo.
__global__ __launch_bounds__(TPB) void tv_persist(
    const float* __restrict__ dx, const float* __restrict__ dy,
    const float* __restrict__ dc, const float* __restrict__ db,
    const float* __restrict__ di, float* __restrict__ out,
    fp16* __restrict__ pub0, fp16* __restrict__ pub1)
{
    __shared__ fp16 s_ub[6][WC];   // rows y0-1 .. y0+4 (idx = r - y0 + 1)
    __shared__ fp16 s_px[4][WC];   // rows y0   .. y0+3
    __shared__ fp16 s_py[5][WC];   // idx0 = shadow row y0-1; idx r+1 = row y0+r
    __shared__ fp16 s_u [4][WC];   // rows y0   .. y0+3   (116,736 B total)

    const int b   = blockIdx.x;
    const int y0  = b * RB;
    const int tid = threadIdx.x;
    const bool hasTop = (b > 0), hasBot = (b < NB - 1);

    const int cx  = tid % CPR;         // chunk column (same for both chunks)
    const int rA  = tid / CPR;         // 0 or 1; thread owns rows rA and rA+2
    const int xc0 = cx * VEC;

    // ---- init: fill LDS state + register invariants from f32 inputs ----
    half8 wxr[2], wyr[2], tbr[2], rcr[2];
    #pragma unroll
    for (int k = 0; k < 2; ++k) {
        int r  = rA + 2 * k;
        int gi = (y0 + r) * WC + xc0;
        float vv[8], cv[8], bv[8], xv[8], yv[8];
        ld8(di, gi, vv); ld8(dc, gi, cv); ld8(db, gi, bv);
        ld8(dx, gi, xv); ld8(dy, gi, yv);
        half8 hub, hz;
        #pragma unroll
        for (int j = 0; j < 8; ++j) {
            hub[j] = (fp16)vv[j];
            wxr[k][j] = (fp16)xv[j];
            wyr[k][j] = (fp16)yv[j];
            tbr[k][j] = (fp16)(TAU * cv[j] * bv[j]);
            rcr[k][j] = (fp16)(1.0f / (1.0f + TAU * cv[j]));
            hz[j] = (fp16)0.f;
        }
        *(half8*)&s_ub[r + 1][xc0] = hub;
        *(half8*)&s_u [r][xc0]     = hub;
        *(half8*)&s_px[r][xc0]     = hz;
        *(half8*)&s_py[r + 1][xc0] = hz;
    }
    half8 wyS = {};
    if (tid < CPR) {
        if (hasTop) {                       // halo row y0-1: ub, shadow py, wy
            int x0 = tid * VEC;
            int gi = (y0 - 1) * WC + x0;
            float vv[8], yv[8];
            ld8(di, gi, vv); ld8(dy, gi, yv);
            half8 h, hz;
            #pragma unroll
            for (int j = 0; j < 8; ++j) { h[j] = (fp16)vv[j]; wyS[j] = (fp16)yv[j]; hz[j] = (fp16)0.f; }
            *(half8*)&s_ub[0][x0] = h;
            *(half8*)&s_py[0][x0] = hz;
        }
    } else {
        if (hasBot) {                       // halo row y0+4: ub
            int x0 = (tid - CPR) * VEC;
            int gi = (y0 + 4) * WC + x0;
            float vv[8];
            ld8(di, gi, vv);
            half8 h;
            #pragma unroll
            for (int j = 0; j < 8; ++j) h[j] = (fp16)vv[j];
            *(half8*)&s_ub[5][x0] = h;
        }
    }
    __syncthreads();

    cg::grid_group grid = cg::this_grid();

    half8 pxn[2], pyn[2];
    for (int t = 0; t < ITS; ++t) {
        // ---------------- dual phase ----------------
        #pragma unroll
        for (int k = 0; k < 2; ++k) {
            int r = rA + 2 * k;
            bool notBot = (y0 + r < H - 1);
            half8 ubC = *(half8*)&s_ub[r + 1][xc0];
            half8 ubN = (cx < CPR - 1) ? *(half8*)&s_ub[r + 1][xc0 + 8] : ubC;
            half8 ubD = *(half8*)&s_ub[r + 2][xc0];   // idx5 = halo (value unused if !notBot)
            half8 pxo = *(half8*)&s_px[r][xc0];
            half8 pyo = *(half8*)&s_py[r + 1][xc0];
            half8 npx, npy;
            #pragma unroll
            for (int j = 0; j < 8; ++j) {
                float ub  = (float)ubC[j];
                float ubR = (j < 5) ? (float)ubC[j + 3] : (float)ubN[j - 5];
                float gx  = (xc0 + j < WC - C) ? (ubR - ub) : 0.0f;
                float gy  = notBot ? ((float)ubD[j] - ub) : 0.0f;
                npx[j] = (fp16)clampw((float)pxo[j] + SIGMA * gx, (float)wxr[k][j]);
                npy[j] = (fp16)clampw((float)pyo[j] + SIGMA * gy, (float)wyr[k][j]);
            }
            *(half8*)&s_px[r][xc0]     = npx;   // safe: only this thread read the old value
            *(half8*)&s_py[r + 1][xc0] = npy;
            pxn[k] = npx; pyn[k] = npy;
        }
        if (hasTop && tid < CPR) {              // shadow py row y0-1
            int x0 = tid * VEC;
            half8 u0 = *(half8*)&s_ub[0][x0];
            half8 u1 = *(half8*)&s_ub[1][x0];
            half8 po = *(half8*)&s_py[0][x0];
            half8 np;
            #pragma unroll
            for (int j = 0; j < 8; ++j)
                np[j] = (fp16)clampw((float)po[j] + SIGMA * ((float)u1[j] - (float)u0[j]),
                                     (float)wyS[j]);
            *(half8*)&s_py[0][x0] = np;
        }
        __syncthreads();

        // ---------------- primal phase ----------------
        #pragma unroll
        for (int k = 0; k < 2; ++k) {
            int r = rA + 2 * k;
            bool notTop = (y0 + r > 0);
            half8 px8 = pxn[k], py8 = pyn[k];
            half8 pxP = (cx > 0) ? *(half8*)&s_px[r][xc0 - 8] : px8;
            half8 pyU = *(half8*)&s_py[r][xc0];   // r=0 -> shadow row
            half8 uo8 = *(half8*)&s_u[r][xc0];
            half8 nu, nub;
            float un8[8];
            #pragma unroll
            for (int j = 0; j < 8; ++j) {
                float d = (float)px8[j] + (float)py8[j];
                float pxL = (j >= 3) ? (float)px8[j - 3] : (float)pxP[j + 5];
                d -= (xc0 + j >= C) ? pxL : 0.0f;
                d -= notTop ? (float)pyU[j] : 0.0f;
                float uo = (float)uo8[j];
                float un = (uo + TAU * d + (float)tbr[k][j]) * (float)rcr[k][j];
                un8[j] = un;
                nu[j]  = (fp16)un;
                nub[j] = (fp16)(2.0f * un - uo);
            }
            *(half8*)&s_u [r][xc0]     = nu;
            *(half8*)&s_ub[r + 1][xc0] = nub;
            if (t == ITS - 1) {
                int gi = (y0 + r) * WC + xc0;
                *(float4*)(out + gi)     = make_float4(un8[0], un8[1], un8[2], un8[3]);
                *(float4*)(out + gi + 4) = make_float4(un8[4], un8[5], un8[6], un8[7]);
            } else {
                fp16* pub = (t & 1) ? pub1 : pub0;
                if (r == 0) *(half8*)&pub[(b * 2 + 0) * WC + xc0] = nub;  // top row
                if (r == 3) *(half8*)&pub[(b * 2 + 1) * WC + xc0] = nub;  // bottom row
            }
        }

        if (t < ITS - 1) {
            __threadfence();
            grid.sync();
            const fp16* pub = (t & 1) ? pub1 : pub0;
            if (tid < CPR) {
                if (hasTop)
                    *(half8*)&s_ub[0][tid * VEC] =
                        *(const half8*)&pub[((b - 1) * 2 + 1) * WC + tid * VEC];
            } else {
                if (hasBot)
                    *(half8*)&s_ub[5][(tid - CPR) * VEC] =
                        *(const half8*)&pub[((b + 1) * 2 + 0) * WC + (tid - CPR) * VEC];
            }
            __syncthreads();
        }
    }
}

extern "C" void kernel_launch(void* const* d_in, const int* in_sizes, int n_in,
                              void* d_out, int out_size, void* d_ws, size_t ws_size,
                              hipStream_t stream) {
    const float* t_dx = (const float*)d_in[0];
    const float* t_dy = (const float*)d_in[1];
    const float* t_dc = (const float*)d_in[2];
    const float* t_db = (const float*)d_in[3];
    const float* t_di = (const float*)d_in[4];
    float* out = (float*)d_out;

    fp16* pub0 = (fp16*)d_ws;                         // 256 blocks x 2 rows x 3072
    fp16* pub1 = pub0 + (size_t)NB * 2 * WC;          // double buffer (3 MB each)

    void* args[] = { (void*)&t_dx, (void*)&t_dy, (void*)&t_dc, (void*)&t_db,
                     (void*)&t_di, (void*)&out, (void*)&pub0, (void*)&pub1 };
    hipLaunchCooperativeKernel((void*)tv_persist, dim3(NB), dim3(TPB),
                               args, 0, stream);
}

// Round 7
// 513.715 us; speedup vs baseline: 3.6778x; 3.6778x over previous
//
#include <hip/hip_runtime.h>
#include <hip/hip_cooperative_groups.h>

#define TAU 0.25f
#define SIGMA 0.5f

typedef _Float16 fp16;
typedef fp16 half8 __attribute__((ext_vector_type(8)));

constexpr int H = 1024, W = 1024, C = 3;
constexpr int N   = H * W * C;     // 3,145,728
constexpr int WC  = W * C;         // 3072 elems per row
constexpr int VEC = 8;
constexpr int CPR = WC / VEC;      // 384 chunks per row
constexpr int TPB = 768;           // threads per block (2 chunks/thread)
constexpr int RB  = 4;             // rows per block
constexpr int NB  = H / RB;        // 256 blocks = 1 per CU
constexpr int ITS = 20;
constexpr int FSTRIDE = 32;        // flag padding: 32 ints = 128 B / block

__device__ __forceinline__ float clampw(float v, float w) {
    return fminf(fmaxf(v, -w), w);
}

__device__ __forceinline__ void ld8(const float* __restrict__ p, int i, float* v) {
    float4 a = *(const float4*)(p + i);
    float4 b = *(const float4*)(p + i + 4);
    v[0]=a.x; v[1]=a.y; v[2]=a.z; v[3]=a.w;
    v[4]=b.x; v[5]=b.y; v[6]=b.z; v[7]=b.w;
}

// Persistent kernel: all 20 CP iterations, state resident in LDS.
// Cross-block dependency (boundary ubar rows) synchronized with per-block
// progress flags (neighbor-only), not a global grid barrier.
__global__ __launch_bounds__(TPB) void tv_persist(
    const float* __restrict__ dx, const float* __restrict__ dy,
    const float* __restrict__ dc, const float* __restrict__ db,
    const float* __restrict__ di, float* __restrict__ out,
    fp16* __restrict__ pub0, fp16* __restrict__ pub1,
    int* __restrict__ prog)
{
    __shared__ fp16 s_ub[6][WC];   // rows y0-1 .. y0+4 (idx = r - y0 + 1)
    __shared__ fp16 s_px[4][WC];   // rows y0   .. y0+3
    __shared__ fp16 s_py[5][WC];   // idx0 = shadow row y0-1; idx r+1 = row y0+r
    __shared__ fp16 s_u [4][WC];   // rows y0   .. y0+3   (116,736 B total)

    const int b   = blockIdx.x;
    const int y0  = b * RB;
    const int tid = threadIdx.x;
    const bool hasTop = (b > 0), hasBot = (b < NB - 1);

    const int cx  = tid % CPR;         // chunk column (same for both chunks)
    const int rA  = tid / CPR;         // 0 or 1; thread owns rows rA and rA+2
    const int xc0 = cx * VEC;

    // ---- init: fill LDS state + register invariants from f32 inputs ----
    half8 wxr[2], wyr[2], tbr[2], rcr[2];
    #pragma unroll
    for (int k = 0; k < 2; ++k) {
        int r  = rA + 2 * k;
        int gi = (y0 + r) * WC + xc0;
        float vv[8], cv[8], bv[8], xv[8], yv[8];
        ld8(di, gi, vv); ld8(dc, gi, cv); ld8(db, gi, bv);
        ld8(dx, gi, xv); ld8(dy, gi, yv);
        half8 hub, hz;
        #pragma unroll
        for (int j = 0; j < 8; ++j) {
            hub[j] = (fp16)vv[j];
            wxr[k][j] = (fp16)xv[j];
            wyr[k][j] = (fp16)yv[j];
            tbr[k][j] = (fp16)(TAU * cv[j] * bv[j]);
            rcr[k][j] = (fp16)(1.0f / (1.0f + TAU * cv[j]));
            hz[j] = (fp16)0.f;
        }
        *(half8*)&s_ub[r + 1][xc0] = hub;
        *(half8*)&s_u [r][xc0]     = hub;
        *(half8*)&s_px[r][xc0]     = hz;
        *(half8*)&s_py[r + 1][xc0] = hz;
    }
    half8 wyS = {};
    if (tid < CPR) {
        if (hasTop) {                       // halo row y0-1: ub, shadow py, wy
            int x0 = tid * VEC;
            int gi = (y0 - 1) * WC + x0;
            float vv[8], yv[8];
            ld8(di, gi, vv); ld8(dy, gi, yv);
            half8 h, hz;
            #pragma unroll
            for (int j = 0; j < 8; ++j) { h[j] = (fp16)vv[j]; wyS[j] = (fp16)yv[j]; hz[j] = (fp16)0.f; }
            *(half8*)&s_ub[0][x0] = h;
            *(half8*)&s_py[0][x0] = hz;
        }
    } else {
        if (hasBot) {                       // halo row y0+4: ub
            int x0 = (tid - CPR) * VEC;
            int gi = (y0 + 4) * WC + x0;
            float vv[8];
            ld8(di, gi, vv);
            half8 h;
            #pragma unroll
            for (int j = 0; j < 8; ++j) h[j] = (fp16)vv[j];
            *(half8*)&s_ub[5][x0] = h;
        }
    }
    __syncthreads();

    half8 pxn[2], pyn[2];
    for (int t = 0; t < ITS; ++t) {
        // ---------------- dual phase ----------------
        #pragma unroll
        for (int k = 0; k < 2; ++k) {
            int r = rA + 2 * k;
            bool notBot = (y0 + r < H - 1);
            half8 ubC = *(half8*)&s_ub[r + 1][xc0];
            half8 ubN = (cx < CPR - 1) ? *(half8*)&s_ub[r + 1][xc0 + 8] : ubC;
            half8 ubD = *(half8*)&s_ub[r + 2][xc0];   // idx5 = halo (unused if !notBot)
            half8 pxo = *(half8*)&s_px[r][xc0];
            half8 pyo = *(half8*)&s_py[r + 1][xc0];
            half8 npx, npy;
            #pragma unroll
            for (int j = 0; j < 8; ++j) {
                float ub  = (float)ubC[j];
                float ubR = (j < 5) ? (float)ubC[j + 3] : (float)ubN[j - 5];
                float gx  = (xc0 + j < WC - C) ? (ubR - ub) : 0.0f;
                float gy  = notBot ? ((float)ubD[j] - ub) : 0.0f;
                npx[j] = (fp16)clampw((float)pxo[j] + SIGMA * gx, (float)wxr[k][j]);
                npy[j] = (fp16)clampw((float)pyo[j] + SIGMA * gy, (float)wyr[k][j]);
            }
            *(half8*)&s_px[r][xc0]     = npx;   // safe: only this thread read the old value
            *(half8*)&s_py[r + 1][xc0] = npy;
            pxn[k] = npx; pyn[k] = npy;
        }
        if (hasTop && tid < CPR) {              // shadow py row y0-1
            int x0 = tid * VEC;
            half8 u0 = *(half8*)&s_ub[0][x0];
            half8 u1 = *(half8*)&s_ub[1][x0];
            half8 po = *(half8*)&s_py[0][x0];
            half8 np;
            #pragma unroll
            for (int j = 0; j < 8; ++j)
                np[j] = (fp16)clampw((float)po[j] + SIGMA * ((float)u1[j] - (float)u0[j]),
                                     (float)wyS[j]);
            *(half8*)&s_py[0][x0] = np;
        }
        __syncthreads();

        // ---------------- primal phase ----------------
        #pragma unroll
        for (int k = 0; k < 2; ++k) {
            int r = rA + 2 * k;
            bool notTop = (y0 + r > 0);
            half8 px8 = pxn[k], py8 = pyn[k];
            half8 pxP = (cx > 0) ? *(half8*)&s_px[r][xc0 - 8] : px8;
            half8 pyU = *(half8*)&s_py[r][xc0];   // r=0 -> shadow row
            half8 uo8 = *(half8*)&s_u[r][xc0];
            half8 nu, nub;
            float un8[8];
            #pragma unroll
            for (int j = 0; j < 8; ++j) {
                float d = (float)px8[j] + (float)py8[j];
                float pxL = (j >= 3) ? (float)px8[j - 3] : (float)pxP[j + 5];
                d -= (xc0 + j >= C) ? pxL : 0.0f;
                d -= notTop ? (float)pyU[j] : 0.0f;
                float uo = (float)uo8[j];
                float un = (uo + TAU * d + (float)tbr[k][j]) * (float)rcr[k][j];
                un8[j] = un;
                nu[j]  = (fp16)un;
                nub[j] = (fp16)(2.0f * un - uo);
            }
            *(half8*)&s_u [r][xc0]     = nu;
            *(half8*)&s_ub[r + 1][xc0] = nub;
            if (t == ITS - 1) {
                int gi = (y0 + r) * WC + xc0;
                *(float4*)(out + gi)     = make_float4(un8[0], un8[1], un8[2], un8[3]);
                *(float4*)(out + gi + 4) = make_float4(un8[4], un8[5], un8[6], un8[7]);
            } else {
                fp16* pub = (t & 1) ? pub1 : pub0;
                if (r == 0) *(half8*)&pub[(b * 2 + 0) * WC + xc0] = nub;  // top row
                if (r == 3) *(half8*)&pub[(b * 2 + 1) * WC + xc0] = nub;  // bottom row
            }
        }

        if (t < ITS - 1) {
            // pub stores drained at this barrier (compiler emits vmcnt(0))
            __syncthreads();
            if (tid == 0) {
                __threadfence();   // write back XCD L2 -> pub rows device-visible
                __hip_atomic_store(prog + b * FSTRIDE, t + 1,
                                   __ATOMIC_RELEASE, __HIP_MEMORY_SCOPE_AGENT);
            }
            // neighbor-only spin (two spinner threads in different waves)
            if (tid == 0 && hasTop) {
                while (__hip_atomic_load(prog + (b - 1) * FSTRIDE,
                                         __ATOMIC_ACQUIRE, __HIP_MEMORY_SCOPE_AGENT) <= t) {}
            }
            if (tid == 64 && hasBot) {
                while (__hip_atomic_load(prog + (b + 1) * FSTRIDE,
                                         __ATOMIC_ACQUIRE, __HIP_MEMORY_SCOPE_AGENT) <= t) {}
            }
            __syncthreads();
            // import halo rows for next iteration
            const fp16* pub = (t & 1) ? pub1 : pub0;
            if (tid < CPR) {
                if (hasTop)
                    *(half8*)&s_ub[0][tid * VEC] =
                        *(const half8*)&pub[((b - 1) * 2 + 1) * WC + tid * VEC];
            } else {
                if (hasBot)
                    *(half8*)&s_ub[5][(tid - CPR) * VEC] =
                        *(const half8*)&pub[((b + 1) * 2 + 0) * WC + (tid - CPR) * VEC];
            }
            __syncthreads();
        }
    }
}

extern "C" void kernel_launch(void* const* d_in, const int* in_sizes, int n_in,
                              void* d_out, int out_size, void* d_ws, size_t ws_size,
                              hipStream_t stream) {
    const float* t_dx = (const float*)d_in[0];
    const float* t_dy = (const float*)d_in[1];
    const float* t_dc = (const float*)d_in[2];
    const float* t_db = (const float*)d_in[3];
    const float* t_di = (const float*)d_in[4];
    float* out = (float*)d_out;

    fp16* pub0 = (fp16*)d_ws;                         // 256 blocks x 2 rows x 3072
    fp16* pub1 = pub0 + (size_t)NB * 2 * WC;          // double buffer (3 MB each)
    int*  prog = (int*)(pub1 + (size_t)NB * 2 * WC);  // padded flags, 32 KB

    // flags must be 0 at kernel start on every (replayed) call
    hipMemsetAsync(prog, 0, NB * FSTRIDE * sizeof(int), stream);

    void* args[] = { (void*)&t_dx, (void*)&t_dy, (void*)&t_dc, (void*)&t_db,
                     (void*)&t_di, (void*)&out, (void*)&pub0, (void*)&pub1,
                     (void*)&prog };
    hipLaunchCooperativeKernel((void*)tv_persist, dim3(NB), dim3(TPB),
                               args, 0, stream);
}

// Round 8
// 132.418 us; speedup vs baseline: 14.2679x; 3.8795x over previous
//
#include <hip/hip_runtime.h>

#define TAU 0.25f
#define SIGMA 0.5f

typedef _Float16 fp16;
typedef fp16 half8 __attribute__((ext_vector_type(8)));

constexpr int H = 1024, W = 1024, C = 3;
constexpr int N   = H * W * C;     // 3,145,728
constexpr int WC  = W * C;         // 3072 elems per row
constexpr int VEC = 8;
constexpr int CPR = WC / VEC;      // 384 chunks per row
constexpr int TPB = 768;           // threads per block (2 chunks/thread)
constexpr int RB  = 4;             // rows per block
constexpr int NB  = H / RB;        // 256 blocks = 1 per CU
constexpr int ITS = 20;
constexpr int FSTRIDE = 32;        // flag padding: 32 ints = 128 B / block

__device__ __forceinline__ float clampw(float v, float w) {
    return fminf(fmaxf(v, -w), w);
}

__device__ __forceinline__ void ld8(const float* __restrict__ p, int i, float* v) {
    float4 a = *(const float4*)(p + i);
    float4 b = *(const float4*)(p + i + 4);
    v[0]=a.x; v[1]=a.y; v[2]=a.z; v[3]=a.w;
    v[4]=b.x; v[5]=b.y; v[6]=b.z; v[7]=b.w;
}

// agent-scope relaxed 16B store/load (sc1 -> coherent at L3, no L2 residue)
__device__ __forceinline__ void pub_store(fp16* dst, half8 v) {
    union { half8 h; unsigned long long q[2]; } cv; cv.h = v;
    __hip_atomic_store((unsigned long long*)dst,     cv.q[0],
                       __ATOMIC_RELAXED, __HIP_MEMORY_SCOPE_AGENT);
    __hip_atomic_store((unsigned long long*)dst + 1, cv.q[1],
                       __ATOMIC_RELAXED, __HIP_MEMORY_SCOPE_AGENT);
}
__device__ __forceinline__ half8 pub_load(const fp16* src) {
    union { unsigned long long q[2]; half8 h; } cv;
    cv.q[0] = __hip_atomic_load((const unsigned long long*)src,
                                __ATOMIC_RELAXED, __HIP_MEMORY_SCOPE_AGENT);
    cv.q[1] = __hip_atomic_load((const unsigned long long*)src + 1,
                                __ATOMIC_RELAXED, __HIP_MEMORY_SCOPE_AGENT);
    return cv.h;
}

// Persistent kernel: all 20 CP iterations, state resident in LDS.
// Cross-block boundary rows exchanged via relaxed agent-scope atomics
// (L2-bypassing), ordered by the vmcnt(0) drain inside __syncthreads().
__global__ __launch_bounds__(TPB) void tv_persist(
    const float* __restrict__ dx, const float* __restrict__ dy,
    const float* __restrict__ dc, const float* __restrict__ db,
    const float* __restrict__ di, float* __restrict__ out,
    fp16* __restrict__ pub0, fp16* __restrict__ pub1,
    int* __restrict__ prog)
{
    __shared__ fp16 s_ub[6][WC];   // rows y0-1 .. y0+4 (idx = r - y0 + 1)
    __shared__ fp16 s_px[4][WC];   // rows y0   .. y0+3
    __shared__ fp16 s_py[5][WC];   // idx0 = shadow row y0-1; idx r+1 = row y0+r
    __shared__ fp16 s_u [4][WC];   // rows y0   .. y0+3   (116,736 B total)

    const int b   = blockIdx.x;
    const int y0  = b * RB;
    const int tid = threadIdx.x;
    const bool hasTop = (b > 0), hasBot = (b < NB - 1);

    const int cx  = tid % CPR;         // chunk column (same for both chunks)
    const int rA  = tid / CPR;         // 0 or 1; thread owns rows rA and rA+2
    const int xc0 = cx * VEC;

    // ---- init: fill LDS state + register invariants from f32 inputs ----
    half8 wxr[2], wyr[2], tbr[2], rcr[2];
    #pragma unroll
    for (int k = 0; k < 2; ++k) {
        int r  = rA + 2 * k;
        int gi = (y0 + r) * WC + xc0;
        float vv[8], cv[8], bv[8], xv[8], yv[8];
        ld8(di, gi, vv); ld8(dc, gi, cv); ld8(db, gi, bv);
        ld8(dx, gi, xv); ld8(dy, gi, yv);
        half8 hub, hz;
        #pragma unroll
        for (int j = 0; j < 8; ++j) {
            hub[j] = (fp16)vv[j];
            wxr[k][j] = (fp16)xv[j];
            wyr[k][j] = (fp16)yv[j];
            tbr[k][j] = (fp16)(TAU * cv[j] * bv[j]);
            rcr[k][j] = (fp16)(1.0f / (1.0f + TAU * cv[j]));
            hz[j] = (fp16)0.f;
        }
        *(half8*)&s_ub[r + 1][xc0] = hub;
        *(half8*)&s_u [r][xc0]     = hub;
        *(half8*)&s_px[r][xc0]     = hz;
        *(half8*)&s_py[r + 1][xc0] = hz;
    }
    half8 wyS = {};
    if (tid < CPR) {
        if (hasTop) {                       // halo row y0-1: ub, shadow py, wy
            int x0 = tid * VEC;
            int gi = (y0 - 1) * WC + x0;
            float vv[8], yv[8];
            ld8(di, gi, vv); ld8(dy, gi, yv);
            half8 h, hz;
            #pragma unroll
            for (int j = 0; j < 8; ++j) { h[j] = (fp16)vv[j]; wyS[j] = (fp16)yv[j]; hz[j] = (fp16)0.f; }
            *(half8*)&s_ub[0][x0] = h;
            *(half8*)&s_py[0][x0] = hz;
        }
    } else {
        if (hasBot) {                       // halo row y0+4: ub
            int x0 = (tid - CPR) * VEC;
            int gi = (y0 + 4) * WC + x0;
            float vv[8];
            ld8(di, gi, vv);
            half8 h;
            #pragma unroll
            for (int j = 0; j < 8; ++j) h[j] = (fp16)vv[j];
            *(half8*)&s_ub[5][x0] = h;
        }
    }
    __syncthreads();

    half8 pxn[2], pyn[2];
    for (int t = 0; t < ITS; ++t) {
        // ---------------- dual phase ----------------
        #pragma unroll
        for (int k = 0; k < 2; ++k) {
            int r = rA + 2 * k;
            bool notBot = (y0 + r < H - 1);
            half8 ubC = *(half8*)&s_ub[r + 1][xc0];
            half8 ubN = (cx < CPR - 1) ? *(half8*)&s_ub[r + 1][xc0 + 8] : ubC;
            half8 ubD = *(half8*)&s_ub[r + 2][xc0];   // idx5 = halo (unused if !notBot)
            half8 pxo = *(half8*)&s_px[r][xc0];
            half8 pyo = *(half8*)&s_py[r + 1][xc0];
            half8 npx, npy;
            #pragma unroll
            for (int j = 0; j < 8; ++j) {
                float ub  = (float)ubC[j];
                float ubR = (j < 5) ? (float)ubC[j + 3] : (float)ubN[j - 5];
                float gx  = (xc0 + j < WC - C) ? (ubR - ub) : 0.0f;
                float gy  = notBot ? ((float)ubD[j] - ub) : 0.0f;
                npx[j] = (fp16)clampw((float)pxo[j] + SIGMA * gx, (float)wxr[k][j]);
                npy[j] = (fp16)clampw((float)pyo[j] + SIGMA * gy, (float)wyr[k][j]);
            }
            *(half8*)&s_px[r][xc0]     = npx;   // safe: only this thread read the old value
            *(half8*)&s_py[r + 1][xc0] = npy;
            pxn[k] = npx; pyn[k] = npy;
        }
        if (hasTop && tid < CPR) {              // shadow py row y0-1
            int x0 = tid * VEC;
            half8 u0 = *(half8*)&s_ub[0][x0];
            half8 u1 = *(half8*)&s_ub[1][x0];
            half8 po = *(half8*)&s_py[0][x0];
            half8 np;
            #pragma unroll
            for (int j = 0; j < 8; ++j)
                np[j] = (fp16)clampw((float)po[j] + SIGMA * ((float)u1[j] - (float)u0[j]),
                                     (float)wyS[j]);
            *(half8*)&s_py[0][x0] = np;
        }
        __syncthreads();

        // ---------------- primal phase ----------------
        #pragma unroll
        for (int k = 0; k < 2; ++k) {
            int r = rA + 2 * k;
            bool notTop = (y0 + r > 0);
            half8 px8 = pxn[k], py8 = pyn[k];
            half8 pxP = (cx > 0) ? *(half8*)&s_px[r][xc0 - 8] : px8;
            half8 pyU = *(half8*)&s_py[r][xc0];   // r=0 -> shadow row
            half8 uo8 = *(half8*)&s_u[r][xc0];
            half8 nu, nub;
            float un8[8];
            #pragma unroll
            for (int j = 0; j < 8; ++j) {
                float d = (float)px8[j] + (float)py8[j];
                float pxL = (j >= 3) ? (float)px8[j - 3] : (float)pxP[j + 5];
                d -= (xc0 + j >= C) ? pxL : 0.0f;
                d -= notTop ? (float)pyU[j] : 0.0f;
                float uo = (float)uo8[j];
                float un = (uo + TAU * d + (float)tbr[k][j]) * (float)rcr[k][j];
                un8[j] = un;
                nu[j]  = (fp16)un;
                nub[j] = (fp16)(2.0f * un - uo);
            }
            *(half8*)&s_u [r][xc0]     = nu;
            *(half8*)&s_ub[r + 1][xc0] = nub;
            if (t == ITS - 1) {
                int gi = (y0 + r) * WC + xc0;
                *(float4*)(out + gi)     = make_float4(un8[0], un8[1], un8[2], un8[3]);
                *(float4*)(out + gi + 4) = make_float4(un8[4], un8[5], un8[6], un8[7]);
            } else {
                fp16* pub = (t & 1) ? pub1 : pub0;
                if (r == 0) pub_store(&pub[(b * 2 + 0) * WC + xc0], nub);  // top row
                if (r == 3) pub_store(&pub[(b * 2 + 1) * WC + xc0], nub);  // bottom row
            }
        }

        if (t < ITS - 1) {
            // all waves' pub stores completed (vmcnt(0) drain) at this barrier;
            // pub stores are agent-scope -> already visible at L3
            __syncthreads();
            if (tid == 0)
                __hip_atomic_store(prog + b * FSTRIDE, t + 1,
                                   __ATOMIC_RELAXED, __HIP_MEMORY_SCOPE_AGENT);
            // neighbor-only spin (relaxed: no L1/L2 invalidate per poll)
            if (tid == 0 && hasTop) {
                while (__hip_atomic_load(prog + (b - 1) * FSTRIDE,
                                         __ATOMIC_RELAXED, __HIP_MEMORY_SCOPE_AGENT) <= t)
                    __builtin_amdgcn_s_sleep(1);
            }
            if (tid == 64 && hasBot) {
                while (__hip_atomic_load(prog + (b + 1) * FSTRIDE,
                                         __ATOMIC_RELAXED, __HIP_MEMORY_SCOPE_AGENT) <= t)
                    __builtin_amdgcn_s_sleep(1);
            }
            __syncthreads();
            // import halo rows (agent-scope loads bypass stale local L1/L2)
            const fp16* pub = (t & 1) ? pub1 : pub0;
            if (tid < CPR) {
                if (hasTop)
                    *(half8*)&s_ub[0][tid * VEC] =
                        pub_load(&pub[((b - 1) * 2 + 1) * WC + tid * VEC]);
            } else {
                if (hasBot)
                    *(half8*)&s_ub[5][(tid - CPR) * VEC] =
                        pub_load(&pub[((b + 1) * 2 + 0) * WC + (tid - CPR) * VEC]);
            }
            __syncthreads();
        }
    }
}

extern "C" void kernel_launch(void* const* d_in, const int* in_sizes, int n_in,
                              void* d_out, int out_size, void* d_ws, size_t ws_size,
                              hipStream_t stream) {
    const float* t_dx = (const float*)d_in[0];
    const float* t_dy = (const float*)d_in[1];
    const float* t_dc = (const float*)d_in[2];
    const float* t_db = (const float*)d_in[3];
    const float* t_di = (const float*)d_in[4];
    float* out = (float*)d_out;

    fp16* pub0 = (fp16*)d_ws;                         // 256 blocks x 2 rows x 3072
    fp16* pub1 = pub0 + (size_t)NB * 2 * WC;          // double buffer (3 MB each)
    int*  prog = (int*)(pub1 + (size_t)NB * 2 * WC);  // padded flags, 32 KB

    // flags must be 0 at kernel start on every (replayed) call
    hipMemsetAsync(prog, 0, NB * FSTRIDE * sizeof(int), stream);

    void* args[] = { (void*)&t_dx, (void*)&t_dy, (void*)&t_dc, (void*)&t_db,
                     (void*)&t_di, (void*)&out, (void*)&pub0, (void*)&pub1,
                     (void*)&prog };
    hipLaunchCooperativeKernel((void*)tv_persist, dim3(NB), dim3(TPB),
                               args, 0, stream);
}